// Round 1
// baseline (2758.485 us; speedup 1.0000x reference)
//
#include <hip/hip_runtime.h>
#include <hip/hip_bf16.h>
#include <math.h>

typedef __hip_bfloat16 bf16;
typedef short bf16x8 __attribute__((ext_vector_type(8)));
typedef float f32x4 __attribute__((ext_vector_type(4)));

__device__ __forceinline__ float sigmoidf_(float x) { return 1.0f / (1.0f + expf(-x)); }

#define NB 8  // batch

// ---------------- staging: NCHW f32 -> NHWC bf16 (padded border +1, padded channels) ----
// out layout: (B, S+2, S+2, Cpad), interior at [y+1][x+1], channel offset coff.
__global__ void k_nchw2nhwc(const float* __restrict__ in, bf16* __restrict__ out,
                            int C, int S, int Cpad, int coff) {
  __shared__ float tile[16][17];
  int Sp = S + 2;
  int xt = blockIdx.x;          // x tile
  int ct = blockIdx.y;          // c tile
  int by = blockIdx.z;          // b*S + y
  int b = by / S, y = by % S;
  int x0 = xt * 16, c0 = ct * 16;
  int tx = threadIdx.x & 15, tc = threadIdx.x >> 4;
  float v = 0.f;
  if (c0 + tc < C && x0 + tx < S)
    v = in[(((size_t)b * C + c0 + tc) * S + y) * S + x0 + tx];
  tile[tc][tx] = v;
  __syncthreads();
  int tcc = threadIdx.x & 15;   // channel within tile (fastest -> coalesced writes)
  int txx = threadIdx.x >> 4;   // x within tile
  if (c0 + tcc < C && x0 + txx < S)
    out[(((size_t)b * Sp + y + 1) * Sp + (x0 + txx + 1)) * Cpad + coff + c0 + tcc]
        = __float2bfloat16(tile[tcc][txx]);
}

// ---------------- weight re-layouts (pads written as zero) ---------------------------
// lstm weights (4CH, CH2, 3, 3) f32 -> Wt[kk][g][Jpad][Cpad] bf16
__global__ void k_wlstm(const float* __restrict__ w, bf16* __restrict__ wt,
                        int CH, int CH2, int Jpad, int Cpad) {
  int idx = blockIdx.x * blockDim.x + threadIdx.x;
  int total = 9 * 4 * Jpad * Cpad;
  if (idx >= total) return;
  int ci = idx % Cpad; int t = idx / Cpad;
  int j = t % Jpad; t /= Jpad;
  int g = t % 4; int kk = t / 4;
  float v = 0.f;
  if (j < CH && ci < CH2)
    v = w[((size_t)(g * CH + j) * CH2 + ci) * 9 + kk];
  wt[idx] = __float2bfloat16(v);
}

// summary weights (C8, C, 3, 3) f32 -> Ws[kk][Npad][Cpad] bf16
__global__ void k_wsum(const float* __restrict__ w, bf16* __restrict__ wt,
                       int C8, int C, int Npad, int Cpad) {
  int idx = blockIdx.x * blockDim.x + threadIdx.x;
  int total = 9 * Npad * Cpad;
  if (idx >= total) return;
  int ci = idx % Cpad; int t = idx / Cpad;
  int co = t % Npad; int kk = t / Npad;
  float v = 0.f;
  if (co < C8 && ci < C)
    v = w[((size_t)co * C + ci) * 9 + kk];
  wt[idx] = __float2bfloat16(v);
}

// ---------------- summary conv GEMM: wave computes 64m x 64n, relu, bf16 -> D ---------
__global__ void __launch_bounds__(64)
k_conv_gemm(const bf16* __restrict__ A,    // (B,Sp,Sp,CpadX) pad1
            const bf16* __restrict__ Wt,   // [kk][Npad][CpadX]
            const float* __restrict__ bias,
            bf16* __restrict__ D,          // (B,Sp,Sp,CpadL) pad1, channels [0,C8)
            int S, int lS, int CpadX, int CpadL, int C8, int Npad, int M) {
  int lane = threadIdx.x;
  int quad = lane >> 4, r = lane & 15;
  int mtile = blockIdx.x, ntile = blockIdx.y;
  int Sp = S + 2;
  size_t abase[4];
#pragma unroll
  for (int s = 0; s < 4; s++) {
    int m = mtile * 64 + s * 16 + r;
    if (m >= M) m = M - 1;
    int b = m >> (2 * lS);
    int rem = m & ((1 << (2 * lS)) - 1);
    int y = rem >> lS, x = rem & ((1 << lS) - 1);
    abase[s] = (((size_t)b * Sp + y) * Sp + x) * CpadX + quad * 8;
  }
  f32x4 acc[4][4] = {};
  int n0 = ntile * 64;
  int KB = CpadX >> 5;
  for (int kk = 0; kk < 9; kk++) {
    int ky = kk / 3, kx = kk % 3;
    size_t aoff = ((size_t)ky * Sp + kx) * CpadX;
    size_t wbase = ((size_t)kk * Npad + n0 + r) * CpadX + quad * 8;
    for (int cb = 0; cb < KB; cb++) {
      bf16x8 af[4], bfr[4];
#pragma unroll
      for (int s = 0; s < 4; s++)
        af[s] = *(const bf16x8*)(A + abase[s] + aoff + cb * 32);
#pragma unroll
      for (int t = 0; t < 4; t++)
        bfr[t] = *(const bf16x8*)(Wt + wbase + (size_t)t * 16 * CpadX + cb * 32);
#pragma unroll
      for (int s = 0; s < 4; s++)
#pragma unroll
        for (int t = 0; t < 4; t++)
          acc[s][t] = __builtin_amdgcn_mfma_f32_16x16x32_bf16(af[s], bfr[t], acc[s][t], 0, 0, 0);
    }
  }
#pragma unroll
  for (int s = 0; s < 4; s++) {
#pragma unroll
    for (int i = 0; i < 4; i++) {
      int m = mtile * 64 + s * 16 + quad * 4 + i;
      if (m >= M) continue;
      int b = m >> (2 * lS);
      int rem = m & ((1 << (2 * lS)) - 1);
      int y = rem >> lS, x = rem & ((1 << lS) - 1);
      size_t dbase = (((size_t)b * Sp + y + 1) * Sp + (x + 1)) * CpadL;
#pragma unroll
      for (int t = 0; t < 4; t++) {
        int co = n0 + t * 16 + r;
        if (co < C8) {
          float v = acc[s][t][i] + bias[co];
          D[dbase + co] = __float2bfloat16(fmaxf(v, 0.f));
        }
      }
    }
  }
}

// ---------------- LSTM conv GEMM: wave computes 64m x (16j x 4gates), fused gates -----
__global__ void __launch_bounds__(64)
k_lstm_gemm(const bf16* __restrict__ A,    // (B,Sp,Sp,CpadL) staged lstm_in
            const bf16* __restrict__ Wt,   // [kk][4][Jpad][CpadL]
            const float* __restrict__ lb,  // (4CH)
            const float* __restrict__ cprev,  // (B,CH,S,S) f32
            float* __restrict__ hout, float* __restrict__ cout,
            int S, int lS, int CpadL, int CH, int Jpad, int M) {
  int lane = threadIdx.x;
  int quad = lane >> 4, r = lane & 15;
  int mtile = blockIdx.x, jt = blockIdx.y;
  int j0 = jt * 16;
  int Sp = S + 2;
  size_t abase[4];
#pragma unroll
  for (int s = 0; s < 4; s++) {
    int m = mtile * 64 + s * 16 + r;
    if (m >= M) m = M - 1;
    int b = m >> (2 * lS);
    int rem = m & ((1 << (2 * lS)) - 1);
    int y = rem >> lS, x = rem & ((1 << lS) - 1);
    abase[s] = (((size_t)b * Sp + y) * Sp + x) * CpadL + quad * 8;
  }
  f32x4 acc[4][4] = {};  // [msub][gate]
  int KB = CpadL >> 5;
  for (int kk = 0; kk < 9; kk++) {
    int ky = kk / 3, kx = kk % 3;
    size_t aoff = ((size_t)ky * Sp + kx) * CpadL;
    size_t wbase = (((size_t)kk * 4) * Jpad + j0 + r) * CpadL + quad * 8;
    for (int cb = 0; cb < KB; cb++) {
      bf16x8 af[4], bfr[4];
#pragma unroll
      for (int s = 0; s < 4; s++)
        af[s] = *(const bf16x8*)(A + abase[s] + aoff + cb * 32);
#pragma unroll
      for (int g = 0; g < 4; g++)
        bfr[g] = *(const bf16x8*)(Wt + wbase + (size_t)g * Jpad * CpadL + cb * 32);
#pragma unroll
      for (int s = 0; s < 4; s++)
#pragma unroll
        for (int g = 0; g < 4; g++)
          acc[s][g] = __builtin_amdgcn_mfma_f32_16x16x32_bf16(af[s], bfr[g], acc[s][g], 0, 0, 0);
    }
  }
  int j = j0 + r;
  bool jok = (j < CH);
  float bi = jok ? lb[j] : 0.f;
  float bf_ = jok ? lb[CH + j] : 0.f;
  float bo = jok ? lb[2 * CH + j] : 0.f;
  float bg = jok ? lb[3 * CH + j] : 0.f;
  if (!jok) return;
#pragma unroll
  for (int s = 0; s < 4; s++) {
#pragma unroll
    for (int i = 0; i < 4; i++) {
      int m = mtile * 64 + s * 16 + quad * 4 + i;
      if (m >= M) continue;
      int b = m >> (2 * lS);
      int rem = m & ((1 << (2 * lS)) - 1);
      int y = rem >> lS, x = rem & ((1 << lS) - 1);
      size_t o = (((size_t)b * CH + j) * S + y) * S + x;
      float ig = sigmoidf_(acc[s][0][i] + bi);
      float fg = sigmoidf_(acc[s][1][i] + bf_);
      float og = sigmoidf_(acc[s][2][i] + bo);
      float gg = tanhf(acc[s][3][i] + bg);
      float cn = fg * cprev[o] + ig * gg;
      hout[o] = og * tanhf(cn);
      cout[o] = cn;
    }
  }
}

// ---------------- correlation (small levels): f32 exact, bf16 copy into staged D -----
__global__ void k_corr(const float* __restrict__ f1, const float* __restrict__ f2,
                       float* __restrict__ corr_out, bf16* __restrict__ D,
                       int C, int S, int CpadL, int C8) {
  int idx = blockIdx.x * blockDim.x + threadIdx.x;
  int total = NB * 49 * S * S;
  if (idx >= total) return;
  int px = idx % S; int t = idx / S;
  int py = t % S; t /= S;
  int d = t % 49; int b = t / 49;
  int qy = py + d / 7 - 3;
  int qx = px + d % 7 - 3;

  float acc = 0.f;
  if (qy >= 0 && qy < S && qx >= 0 && qx < S) {
    const float* p1 = f1 + ((size_t)b * C * S + py) * S + px;
    const float* p2 = f2 + ((size_t)b * C * S + qy) * S + qx;
    size_t cs = (size_t)S * S;
    for (int ci = 0; ci < C; ci++) {
      acc += p1[(size_t)ci * cs] * p2[(size_t)ci * cs];
    }
  }
  float lr = (acc > 0.f) ? acc : 0.01f * acc;
  corr_out[idx] = lr;
  int Sp = S + 2;
  D[(((size_t)b * Sp + py + 1) * Sp + (px + 1)) * CpadL + C8 + d] = __float2bfloat16(lr);
}

// ---------------- correlation (big levels): LDS-tiled, all 49 disp per f2-tile load --
// grid: (B * S/TH, Csplit); block 256 = TH rows x S cols; channels [cs*CB, (cs+1)*CB)
// partial[cs][b][49][y][x] written fully (no memset needed).
template<int S, int TH, int CB>
__global__ void __launch_bounds__(256)
k_corr_tile(const float* __restrict__ f1, const float* __restrict__ f2,
            float* __restrict__ partial, int C) {
  constexpr int W = S + 6;
  constexpr int HH = TH + 6;
  __shared__ float sf2[8 * HH * W];
  constexpr int NRB = S / TH;
  int b = blockIdx.x / NRB;
  int rb = blockIdx.x % NRB;
  int cs = blockIdx.y;
  int y0 = rb * TH;
  int tx = threadIdx.x % S;
  int ty = threadIdx.x / S;
  constexpr size_t CS2 = (size_t)S * S;

  float acc[49];
#pragma unroll
  for (int d = 0; d < 49; d++) acc[d] = 0.f;

  int c0 = cs * CB;
  for (int cb = 0; cb < CB; cb += 8) {
    // f1: own pixel, 8 channels -> regs (coalesced across lanes per channel)
    const float* p1 = f1 + (((size_t)b * C + c0 + cb) * S + (y0 + ty)) * S + tx;
    float f1r[8];
#pragma unroll
    for (int cc = 0; cc < 8; cc++) f1r[cc] = p1[cc * CS2];
    // f2 tile with 3-halo -> LDS (zero-filled OOB)
    const float* f2b = f2 + ((size_t)b * C + c0 + cb) * CS2;
    constexpr int TOT = 8 * HH * W;
    for (int i = threadIdx.x; i < TOT; i += 256) {
      int xx = i % W; int t2 = i / W; int yy = t2 % HH; int cc = t2 / HH;
      int gy = y0 + yy - 3, gx = xx - 3;
      float v = 0.f;
      if (gy >= 0 && gy < S && gx >= 0 && gx < S)
        v = f2b[cc * CS2 + (size_t)gy * S + gx];
      sf2[(cc * HH + yy) * W + xx] = v;
    }
    __syncthreads();
#pragma unroll
    for (int cc = 0; cc < 8; cc++) {
      float a = f1r[cc];
      const float* srow = sf2 + cc * HH * W + ty * W + tx;  // constexpr W -> imm offsets
#pragma unroll
      for (int dy = 0; dy < 7; dy++)
#pragma unroll
        for (int dx = 0; dx < 7; dx++)
          acc[dy * 7 + dx] += a * srow[dy * W + dx];
    }
    __syncthreads();
  }

  float* pp = partial + (((size_t)cs * NB + b) * 49) * CS2 + (size_t)(y0 + ty) * S + tx;
#pragma unroll
  for (int d = 0; d < 49; d++)
    pp[(size_t)d * CS2] = acc[d];
}

// sum partials over Csplit, leaky-relu, write f32 out + bf16 into staged D
__global__ void k_corr_reduce(const float* __restrict__ partial,
                              float* __restrict__ corr_out, bf16* __restrict__ D,
                              int S, int Csplit, int CpadL, int C8) {
  int idx = blockIdx.x * blockDim.x + threadIdx.x;
  int total = NB * 49 * S * S;
  if (idx >= total) return;
  size_t slice = (size_t)NB * 49 * S * S;
  float acc = 0.f;
  for (int cs = 0; cs < Csplit; cs++) acc += partial[(size_t)cs * slice + idx];
  float lr = (acc > 0.f) ? acc : 0.01f * acc;
  corr_out[idx] = lr;
  int px = idx % S; int t = idx / S;
  int py = t % S; t /= S;
  int d = t % 49; int b = t / 49;
  int Sp = S + 2;
  D[(((size_t)b * Sp + py + 1) * Sp + (px + 1)) * CpadL + C8 + d] = __float2bfloat16(lr);
}

extern "C" void kernel_launch(void* const* d_in, const int* in_sizes, int n_in,
                              void* d_out, int out_size, void* d_ws, size_t ws_size,
                              hipStream_t stream) {
  (void)in_sizes; (void)n_in; (void)out_size; (void)ws_size;
  static const int CINa[6] = {512, 1024, 512, 256, 256, 256};
  static const int Sa[6]   = {64, 32, 16, 8, 4, 2};
  static const int lSa[6]  = {6, 5, 4, 3, 2, 1};
  static const int CHa[6]  = {113, 177, 113, 81, 81, 81};
  static const int CpadLa[6] = {256, 384, 256, 192, 192, 192};  // 2*CH -> mult of 32
  static const int Jpada[6]  = {128, 192, 128, 96, 96, 96};     // CH -> mult of 16
  const int B = 8;

  size_t h_off[6], c_off[6], corr_off[6];
  size_t off = 0;
  for (int i = 0; i < 6; i++) { h_off[i] = off;    off += (size_t)B * CHa[i] * Sa[i] * Sa[i]; }
  for (int i = 0; i < 6; i++) { c_off[i] = off;    off += (size_t)B * CHa[i] * Sa[i] * Sa[i]; }
  for (int i = 0; i < 6; i++) { corr_off[i] = off; off += (size_t)B * 49 * Sa[i] * Sa[i]; }

  float* out = (float*)d_out;
  char* ws = (char*)d_ws;
  // arena: A (x NHWC pad1) 36MB | D (lstm_in NHWC pad1) 18MB | Wsum 3MB | Wlstm 6MB | corr partials 51.4MB
  const size_t offA = 0;
  const size_t offD = 37748736;
  const size_t offWs = offD + 18874368;
  const size_t offWl = offWs + 3145728;
  const size_t offP = offWl + 6291456;

  for (int i = 0; i < 6; i++) {
    const float* x  = (const float*)d_in[8 * i + 0];
    const float* xp = (const float*)d_in[8 * i + 1];
    const float* h  = (const float*)d_in[8 * i + 2];
    const float* c  = (const float*)d_in[8 * i + 3];
    const float* sw = (const float*)d_in[8 * i + 4];
    const float* sb = (const float*)d_in[8 * i + 5];
    const float* lw = (const float*)d_in[8 * i + 6];
    const float* lb = (const float*)d_in[8 * i + 7];
    int C = CINa[i], S = Sa[i], lS = lSa[i], CH = CHa[i], C8 = C / 8;
    int CH2 = 2 * CH, CpadL = CpadLa[i], Jpad = Jpada[i];
    int Sp = S + 2;
    int Npad = (C8 + 63) / 64 * 64;
    int M = B * S * S;
    int Mtiles = (M + 63) / 64;

    bf16* Abuf = (bf16*)(ws + offA);
    bf16* Dbuf = (bf16*)(ws + offD);
    bf16* Wsum = (bf16*)(ws + offWs);
    bf16* Wlstm = (bf16*)(ws + offWl);
    float* Pbuf = (float*)(ws + offP);

    size_t sizeA = (size_t)B * Sp * Sp * C * 2;
    size_t sizeD = (size_t)B * Sp * Sp * CpadL * 2;
    hipMemsetAsync(Abuf, 0, sizeA, stream);
    hipMemsetAsync(Dbuf, 0, sizeD, stream);

    // x -> A (NHWC bf16, pad1); CpadX == C (all multiples of 32)
    {
      dim3 g((S + 15) / 16, (C + 15) / 16, B * S);
      k_nchw2nhwc<<<g, 256, 0, stream>>>(x, Abuf, C, S, C, 0);
    }
    // summary weights
    {
      int tot = 9 * Npad * C;
      k_wsum<<<(tot + 255) / 256, 256, 0, stream>>>(sw, Wsum, C8, C, Npad, C);
    }
    // summary GEMM -> D channels [0, C8)
    {
      dim3 g(Mtiles, Npad / 64);
      k_conv_gemm<<<g, 64, 0, stream>>>(Abuf, Wsum, sb, Dbuf, S, lS, C, CpadL, C8, Npad, M);
    }
    // correlation -> d_out (f32) + D channels [C8, C8+49)
    if (i == 0) {
      // S=64, TH=4, Csplit=8, CB=64
      dim3 g(B * (64 / 4), 8);
      k_corr_tile<64, 4, 64><<<g, 256, 0, stream>>>(x, xp, Pbuf, C);
      int tot = B * 49 * S * S;
      k_corr_reduce<<<(tot + 255) / 256, 256, 0, stream>>>(Pbuf, out + corr_off[i], Dbuf,
                                                           S, 8, CpadL, C8);
    } else if (i == 1) {
      // S=32, TH=8, Csplit=16, CB=64
      dim3 g(B * (32 / 8), 16);
      k_corr_tile<32, 8, 64><<<g, 256, 0, stream>>>(x, xp, Pbuf, C);
      int tot = B * 49 * S * S;
      k_corr_reduce<<<(tot + 255) / 256, 256, 0, stream>>>(Pbuf, out + corr_off[i], Dbuf,
                                                           S, 16, CpadL, C8);
    } else if (i == 2) {
      // S=16, TH=16, Csplit=16, CB=32
      dim3 g(B * (16 / 16), 16);
      k_corr_tile<16, 16, 32><<<g, 256, 0, stream>>>(x, xp, Pbuf, C);
      int tot = B * 49 * S * S;
      k_corr_reduce<<<(tot + 255) / 256, 256, 0, stream>>>(Pbuf, out + corr_off[i], Dbuf,
                                                           S, 16, CpadL, C8);
    } else {
      int tot = B * 49 * S * S;
      k_corr<<<(tot + 255) / 256, 256, 0, stream>>>(x, xp, out + corr_off[i], Dbuf,
                                                    C, S, CpadL, C8);
    }
    // h -> D channels [C8+49, 2CH)
    {
      dim3 g((S + 15) / 16, (CH + 15) / 16, B * S);
      k_nchw2nhwc<<<g, 256, 0, stream>>>(h, Dbuf, CH, S, CpadL, C8 + 49);
    }
    // lstm weights
    {
      int tot = 9 * 4 * Jpad * CpadL;
      k_wlstm<<<(tot + 255) / 256, 256, 0, stream>>>(lw, Wlstm, CH, CH2, Jpad, CpadL);
    }
    // LSTM GEMM + fused gates
    {
      dim3 g(Mtiles, Jpad / 16);
      k_lstm_gemm<<<g, 64, 0, stream>>>(Dbuf, Wlstm, lb, c,
                                        out + h_off[i], out + c_off[i],
                                        S, lS, CpadL, CH, Jpad, M);
    }
  }
}

// Round 2
// 2353.123 us; speedup vs baseline: 1.1723x; 1.1723x over previous
//
#include <hip/hip_runtime.h>
#include <math.h>

typedef _Float16 f16;
typedef _Float16 f16x8 __attribute__((ext_vector_type(8)));
typedef float f32x4 __attribute__((ext_vector_type(4)));

__device__ __forceinline__ float sigmoidf_(float x) { return 1.0f / (1.0f + expf(-x)); }

#define NB 8  // batch

// ---------------- staging: NCHW f32 -> NHWC f16 (parametric pad, padded channels) ----
// out layout: (B, S+2p, S+2p, Cpad), interior at [y+pad][x+pad], channel offset coff.
__global__ void k_nchw2nhwc(const float* __restrict__ in, f16* __restrict__ out,
                            int C, int S, int Cpad, int coff, int Wp, int pad) {
  __shared__ float tile[16][17];
  int xt = blockIdx.x;          // x tile
  int ct = blockIdx.y;          // c tile
  int by = blockIdx.z;          // b*S + y
  int b = by / S, y = by % S;
  int x0 = xt * 16, c0 = ct * 16;
  int tx = threadIdx.x & 15, tc = threadIdx.x >> 4;
  float v = 0.f;
  if (c0 + tc < C && x0 + tx < S)
    v = in[(((size_t)b * C + c0 + tc) * S + y) * S + x0 + tx];
  tile[tc][tx] = v;
  __syncthreads();
  int tcc = threadIdx.x & 15;   // channel within tile (fastest -> coalesced writes)
  int txx = threadIdx.x >> 4;   // x within tile
  if (c0 + tcc < C && x0 + txx < S)
    out[(((size_t)b * Wp + y + pad) * Wp + (x0 + txx + pad)) * Cpad + coff + c0 + tcc]
        = (f16)tile[tcc][txx];
}

// ---------------- weight re-layouts (pads written as zero) ---------------------------
// lstm weights (4CH, CH2, 3, 3) f32 -> Wt[kk][g][Jpad][Cpad] f16
__global__ void k_wlstm(const float* __restrict__ w, f16* __restrict__ wt,
                        int CH, int CH2, int Jpad, int Cpad) {
  int idx = blockIdx.x * blockDim.x + threadIdx.x;
  int total = 9 * 4 * Jpad * Cpad;
  if (idx >= total) return;
  int ci = idx % Cpad; int t = idx / Cpad;
  int j = t % Jpad; t /= Jpad;
  int g = t % 4; int kk = t / 4;
  float v = 0.f;
  if (j < CH && ci < CH2)
    v = w[((size_t)(g * CH + j) * CH2 + ci) * 9 + kk];
  wt[idx] = (f16)v;
}

// summary weights (C8, C, 3, 3) f32 -> Ws[kk][Npad][Cpad] f16
__global__ void k_wsum(const float* __restrict__ w, f16* __restrict__ wt,
                       int C8, int C, int Npad, int Cpad) {
  int idx = blockIdx.x * blockDim.x + threadIdx.x;
  int total = 9 * Npad * Cpad;
  if (idx >= total) return;
  int ci = idx % Cpad; int t = idx / Cpad;
  int co = t % Npad; int kk = t / Npad;
  float v = 0.f;
  if (co < C8 && ci < C)
    v = w[((size_t)co * C + ci) * 9 + kk];
  wt[idx] = (f16)v;
}

// ---------------- summary conv GEMM: wave computes 64m x 64n, relu, f16 -> D ---------
__global__ void __launch_bounds__(64)
k_conv_gemm(const f16* __restrict__ A,     // (B,Sp,Sp,CpadX) pad1
            const f16* __restrict__ Wt,    // [kk][Npad][CpadX]
            const float* __restrict__ bias,
            f16* __restrict__ D,           // (B,Sp,Sp,CpadL) pad1, channels [0,C8)
            int S, int lS, int CpadX, int CpadL, int C8, int Npad, int M) {
  int lane = threadIdx.x;
  int quad = lane >> 4, r = lane & 15;
  int mtile = blockIdx.x, ntile = blockIdx.y;
  int Sp = S + 2;
  size_t abase[4];
#pragma unroll
  for (int s = 0; s < 4; s++) {
    int m = mtile * 64 + s * 16 + r;
    if (m >= M) m = M - 1;
    int b = m >> (2 * lS);
    int rem = m & ((1 << (2 * lS)) - 1);
    int y = rem >> lS, x = rem & ((1 << lS) - 1);
    abase[s] = (((size_t)b * Sp + y) * Sp + x) * CpadX + quad * 8;
  }
  f32x4 acc[4][4] = {};
  int n0 = ntile * 64;
  int KB = CpadX >> 5;
  for (int kk = 0; kk < 9; kk++) {
    int ky = kk / 3, kx = kk % 3;
    size_t aoff = ((size_t)ky * Sp + kx) * CpadX;
    size_t wbase = ((size_t)kk * Npad + n0 + r) * CpadX + quad * 8;
    for (int cb = 0; cb < KB; cb++) {
      f16x8 af[4], bfr[4];
#pragma unroll
      for (int s = 0; s < 4; s++)
        af[s] = *(const f16x8*)(A + abase[s] + aoff + cb * 32);
#pragma unroll
      for (int t = 0; t < 4; t++)
        bfr[t] = *(const f16x8*)(Wt + wbase + (size_t)t * 16 * CpadX + cb * 32);
#pragma unroll
      for (int s = 0; s < 4; s++)
#pragma unroll
        for (int t = 0; t < 4; t++)
          acc[s][t] = __builtin_amdgcn_mfma_f32_16x16x32_f16(af[s], bfr[t], acc[s][t], 0, 0, 0);
    }
  }
#pragma unroll
  for (int s = 0; s < 4; s++) {
#pragma unroll
    for (int i = 0; i < 4; i++) {
      int m = mtile * 64 + s * 16 + quad * 4 + i;
      if (m >= M) continue;
      int b = m >> (2 * lS);
      int rem = m & ((1 << (2 * lS)) - 1);
      int y = rem >> lS, x = rem & ((1 << lS) - 1);
      size_t dbase = (((size_t)b * Sp + y + 1) * Sp + (x + 1)) * CpadL;
#pragma unroll
      for (int t = 0; t < 4; t++) {
        int co = n0 + t * 16 + r;
        if (co < C8) {
          float v = acc[s][t][i] + bias[co];
          D[dbase + co] = (f16)fmaxf(v, 0.f);
        }
      }
    }
  }
}

// ---------------- LSTM conv GEMM: wave computes 64m x (16j x 4gates), fused gates -----
__global__ void __launch_bounds__(64)
k_lstm_gemm(const f16* __restrict__ A,     // (B,Sp,Sp,CpadL) staged lstm_in
            const f16* __restrict__ Wt,    // [kk][4][Jpad][CpadL]
            const float* __restrict__ lb,  // (4CH)
            const float* __restrict__ cprev,  // (B,CH,S,S) f32
            float* __restrict__ hout, float* __restrict__ cout,
            int S, int lS, int CpadL, int CH, int Jpad, int M) {
  int lane = threadIdx.x;
  int quad = lane >> 4, r = lane & 15;
  int mtile = blockIdx.x, jt = blockIdx.y;
  int j0 = jt * 16;
  int Sp = S + 2;
  size_t abase[4];
#pragma unroll
  for (int s = 0; s < 4; s++) {
    int m = mtile * 64 + s * 16 + r;
    if (m >= M) m = M - 1;
    int b = m >> (2 * lS);
    int rem = m & ((1 << (2 * lS)) - 1);
    int y = rem >> lS, x = rem & ((1 << lS) - 1);
    abase[s] = (((size_t)b * Sp + y) * Sp + x) * CpadL + quad * 8;
  }
  f32x4 acc[4][4] = {};  // [msub][gate]
  int KB = CpadL >> 5;
  for (int kk = 0; kk < 9; kk++) {
    int ky = kk / 3, kx = kk % 3;
    size_t aoff = ((size_t)ky * Sp + kx) * CpadL;
    size_t wbase = (((size_t)kk * 4) * Jpad + j0 + r) * CpadL + quad * 8;
    for (int cb = 0; cb < KB; cb++) {
      f16x8 af[4], bfr[4];
#pragma unroll
      for (int s = 0; s < 4; s++)
        af[s] = *(const f16x8*)(A + abase[s] + aoff + cb * 32);
#pragma unroll
      for (int g = 0; g < 4; g++)
        bfr[g] = *(const f16x8*)(Wt + wbase + (size_t)g * Jpad * CpadL + cb * 32);
#pragma unroll
      for (int s = 0; s < 4; s++)
#pragma unroll
        for (int g = 0; g < 4; g++)
          acc[s][g] = __builtin_amdgcn_mfma_f32_16x16x32_f16(af[s], bfr[g], acc[s][g], 0, 0, 0);
    }
  }
  int j = j0 + r;
  bool jok = (j < CH);
  if (!jok) return;
  float bi = lb[j];
  float bf_ = lb[CH + j];
  float bo = lb[2 * CH + j];
  float bg = lb[3 * CH + j];
#pragma unroll
  for (int s = 0; s < 4; s++) {
#pragma unroll
    for (int i = 0; i < 4; i++) {
      int m = mtile * 64 + s * 16 + quad * 4 + i;
      if (m >= M) continue;
      int b = m >> (2 * lS);
      int rem = m & ((1 << (2 * lS)) - 1);
      int y = rem >> lS, x = rem & ((1 << lS) - 1);
      size_t o = (((size_t)b * CH + j) * S + y) * S + x;
      float ig = sigmoidf_(acc[s][0][i] + bi);
      float fg = sigmoidf_(acc[s][1][i] + bf_);
      float og = sigmoidf_(acc[s][2][i] + bo);
      float gg = tanhf(acc[s][3][i] + bg);
      float cn = fg * cprev[o] + ig * gg;
      hout[o] = og * tanhf(cn);
      cout[o] = cn;
    }
  }
}

// ---------------- correlation (small levels 3-5): f32 exact, f16 copy into staged D --
__global__ void k_corr(const float* __restrict__ f1, const float* __restrict__ f2,
                       float* __restrict__ corr_out, f16* __restrict__ D,
                       int C, int S, int CpadL, int C8) {
  int idx = blockIdx.x * blockDim.x + threadIdx.x;
  int total = NB * 49 * S * S;
  if (idx >= total) return;
  int px = idx % S; int t = idx / S;
  int py = t % S; t /= S;
  int d = t % 49; int b = t / 49;
  int qy = py + d / 7 - 3;
  int qx = px + d % 7 - 3;

  float acc = 0.f;
  if (qy >= 0 && qy < S && qx >= 0 && qx < S) {
    const float* p1 = f1 + ((size_t)b * C * S + py) * S + px;
    const float* p2 = f2 + ((size_t)b * C * S + qy) * S + qx;
    size_t cs = (size_t)S * S;
    for (int ci = 0; ci < C; ci++) {
      acc += p1[(size_t)ci * cs] * p2[(size_t)ci * cs];
    }
  }
  float lr = (acc > 0.f) ? acc : 0.01f * acc;
  corr_out[idx] = lr;
  int Sp = S + 2;
  D[(((size_t)b * Sp + py + 1) * Sp + (px + 1)) * CpadL + C8 + d] = (f16)lr;
}

// ---------------- correlation (big levels 0-2): banded MFMA Gram tiles ---------------
// One wave per A-tile (16 consecutive x of one row). acc[dy][t] = f1_tile . f2_tile^T
// over channels; band n-m in [-3,3] extracted in epilogue -> 49 displacements.
// A: f1 staged NHWC pad1 (Sp=S+2). A2: f2 staged NHWC pad3 (Sq=S+6, zero border).
template<int S>
__global__ void __launch_bounds__(256)
k_corr_mfma(const f16* __restrict__ A,     // (B,S+2,S+2,C)
            const f16* __restrict__ A2,    // (B,S+6,S+6,C)
            float* __restrict__ corr_out,  // (B,49,S,S)
            f16* __restrict__ D,           // (B,S+2,S+2,CpadL), channels [C8,C8+49)
            int C, int CpadL, int C8) {
  constexpr int XT = S / 16;
  constexpr int Sp = S + 2, Sq = S + 6;
  // chunked XCD swizzle: gridDim.x divisible by 8 -> each XCD gets one contiguous
  // slice (= whole batches; f2 slice per batch fits one XCD L2).
  int nb = gridDim.x;
  int eb = (blockIdx.x % 8) * (nb / 8) + blockIdx.x / 8;
  int wid = eb * 4 + (threadIdx.x >> 6);
  int lane = threadIdx.x & 63;
  int quad = lane >> 4, r = lane & 15;
  int xt = wid % XT; int t1 = wid / XT;
  int y = t1 % S; int b = t1 / S;
  int x0 = xt * 16;

  // A-frag: lane r holds f1 pixel (y, x0+r), k = quad*8..
  const f16* pa = A + (((size_t)b * Sp + (y + 1)) * Sp + (x0 + r + 1)) * C + quad * 8;
  // B-frags: lane r holds f2 pixel; t=0 at padded x = x0+r, t=1 at x0+16+r (clamped
  // into the right zero-pad; clamped lanes fall outside the extracted band anyway).
  int xs1 = x0 + 16 + r; if (xs1 > S + 5) xs1 = S + 5;
  size_t off0 = (size_t)(x0 + r) * C + (size_t)quad * 8;
  size_t off1 = (size_t)xs1 * C + (size_t)quad * 8;
  const f16* pb = A2 + ((size_t)b * Sq + y) * Sq * C;  // padded row y+0 base

  f32x4 acc[7][2] = {};
  for (int cb = 0; cb < C; cb += 32) {
    f16x8 af = *(const f16x8*)(pa + cb);
#pragma unroll
    for (int dyo = 0; dyo < 7; dyo++) {
      const f16* pr = pb + (size_t)dyo * Sq * C + cb;
      f16x8 b0 = *(const f16x8*)(pr + off0);
      f16x8 b1 = *(const f16x8*)(pr + off1);
      acc[dyo][0] = __builtin_amdgcn_mfma_f32_16x16x32_f16(af, b0, acc[dyo][0], 0, 0, 0);
      acc[dyo][1] = __builtin_amdgcn_mfma_f32_16x16x32_f16(af, b1, acc[dyo][1], 0, 0, 0);
    }
  }
  // epilogue: band extract. D[m][n]: m = quad*4+i, n = r.
  // t=0: f2x = x0-3+r  -> dx = r-m;    t=1: f2x = x0+13+r -> dx = r-m+16.
#pragma unroll
  for (int dyo = 0; dyo < 7; dyo++) {
#pragma unroll
    for (int t = 0; t < 2; t++) {
#pragma unroll
      for (int i = 0; i < 4; i++) {
        int ml = quad * 4 + i;
        int dxo = r - ml + t * 16;
        if (dxo < 0 || dxo > 6) continue;
        float v = acc[dyo][t][i];
        float lr = (v > 0.f) ? v : 0.01f * v;
        int d = dyo * 7 + dxo;
        int x = x0 + ml;
        corr_out[(((size_t)b * 49 + d) * S + y) * S + x] = lr;
        D[(((size_t)b * Sp + y + 1) * Sp + (x + 1)) * CpadL + C8 + d] = (f16)lr;
      }
    }
  }
}

extern "C" void kernel_launch(void* const* d_in, const int* in_sizes, int n_in,
                              void* d_out, int out_size, void* d_ws, size_t ws_size,
                              hipStream_t stream) {
  (void)in_sizes; (void)n_in; (void)out_size; (void)ws_size;
  static const int CINa[6] = {512, 1024, 512, 256, 256, 256};
  static const int Sa[6]   = {64, 32, 16, 8, 4, 2};
  static const int lSa[6]  = {6, 5, 4, 3, 2, 1};
  static const int CHa[6]  = {113, 177, 113, 81, 81, 81};
  static const int CpadLa[6] = {256, 384, 256, 192, 192, 192};  // 2*CH -> mult of 32
  static const int Jpada[6]  = {128, 192, 128, 96, 96, 96};     // CH -> mult of 16
  const int B = 8;

  size_t h_off[6], c_off[6], corr_off[6];
  size_t off = 0;
  for (int i = 0; i < 6; i++) { h_off[i] = off;    off += (size_t)B * CHa[i] * Sa[i] * Sa[i]; }
  for (int i = 0; i < 6; i++) { c_off[i] = off;    off += (size_t)B * CHa[i] * Sa[i] * Sa[i]; }
  for (int i = 0; i < 6; i++) { corr_off[i] = off; off += (size_t)B * 49 * Sa[i] * Sa[i]; }

  float* out = (float*)d_out;
  char* ws = (char*)d_ws;
  // arena: A (x NHWC pad1) 36MB | D (lstm_in NHWC pad1) 18MB | Wsum 3MB | Wlstm 6MB |
  //        A2 (xp NHWC pad3, levels 0-2) max 40.2MB  -> total ~103.3MB
  const size_t offA = 0;
  const size_t offD = 37748736;
  const size_t offWs = offD + 18874368;
  const size_t offWl = offWs + 3145728;
  const size_t offA2 = offWl + 6291456;

  for (int i = 0; i < 6; i++) {
    const float* x  = (const float*)d_in[8 * i + 0];
    const float* xp = (const float*)d_in[8 * i + 1];
    const float* h  = (const float*)d_in[8 * i + 2];
    const float* c  = (const float*)d_in[8 * i + 3];
    const float* sw = (const float*)d_in[8 * i + 4];
    const float* sb = (const float*)d_in[8 * i + 5];
    const float* lw = (const float*)d_in[8 * i + 6];
    const float* lb = (const float*)d_in[8 * i + 7];
    int C = CINa[i], S = Sa[i], lS = lSa[i], CH = CHa[i], C8 = C / 8;
    int CH2 = 2 * CH, CpadL = CpadLa[i], Jpad = Jpada[i];
    int Sp = S + 2;
    int Npad = (C8 + 63) / 64 * 64;
    int M = B * S * S;
    int Mtiles = (M + 63) / 64;

    f16* Abuf = (f16*)(ws + offA);
    f16* Dbuf = (f16*)(ws + offD);
    f16* Wsum = (f16*)(ws + offWs);
    f16* Wlstm = (f16*)(ws + offWl);
    f16* A2buf = (f16*)(ws + offA2);

    size_t sizeA = (size_t)B * Sp * Sp * C * 2;
    size_t sizeD = (size_t)B * Sp * Sp * CpadL * 2;
    hipMemsetAsync(Abuf, 0, sizeA, stream);
    hipMemsetAsync(Dbuf, 0, sizeD, stream);

    // x -> A (NHWC f16, pad1); CpadX == C (all multiples of 32)
    {
      dim3 g((S + 15) / 16, (C + 15) / 16, B * S);
      k_nchw2nhwc<<<g, 256, 0, stream>>>(x, Abuf, C, S, C, 0, Sp, 1);
    }
    // summary weights
    {
      int tot = 9 * Npad * C;
      k_wsum<<<(tot + 255) / 256, 256, 0, stream>>>(sw, Wsum, C8, C, Npad, C);
    }
    // summary GEMM -> D channels [0, C8)
    {
      dim3 g(Mtiles, Npad / 64);
      k_conv_gemm<<<g, 64, 0, stream>>>(Abuf, Wsum, sb, Dbuf, S, lS, C, CpadL, C8, Npad, M);
    }
    // correlation -> d_out (f32) + D channels [C8, C8+49)
    if (i < 3) {
      int Sq = S + 6;
      size_t sizeA2 = (size_t)B * Sq * Sq * C * 2;
      hipMemsetAsync(A2buf, 0, sizeA2, stream);
      {
        dim3 g((S + 15) / 16, (C + 15) / 16, B * S);
        k_nchw2nhwc<<<g, 256, 0, stream>>>(xp, A2buf, C, S, C, 0, Sq, 3);
      }
      int blocks = B * S * (S / 16) / 4;   // one wave per 16-pixel A-tile
      if (i == 0)
        k_corr_mfma<64><<<blocks, 256, 0, stream>>>(Abuf, A2buf, out + corr_off[i], Dbuf,
                                                    C, CpadL, C8);
      else if (i == 1)
        k_corr_mfma<32><<<blocks, 256, 0, stream>>>(Abuf, A2buf, out + corr_off[i], Dbuf,
                                                    C, CpadL, C8);
      else
        k_corr_mfma<16><<<blocks, 256, 0, stream>>>(Abuf, A2buf, out + corr_off[i], Dbuf,
                                                    C, CpadL, C8);
    } else {
      int tot = B * 49 * S * S;
      k_corr<<<(tot + 255) / 256, 256, 0, stream>>>(x, xp, out + corr_off[i], Dbuf,
                                                    C, S, CpadL, C8);
    }
    // h -> D channels [C8+49, 2CH)
    {
      dim3 g((S + 15) / 16, (CH + 15) / 16, B * S);
      k_nchw2nhwc<<<g, 256, 0, stream>>>(h, Dbuf, CH, S, CpadL, C8 + 49, Sp, 1);
    }
    // lstm weights
    {
      int tot = 9 * 4 * Jpad * CpadL;
      k_wlstm<<<(tot + 255) / 256, 256, 0, stream>>>(lw, Wlstm, CH, CH2, Jpad, CpadL);
    }
    // LSTM GEMM + fused gates
    {
      dim3 g(Mtiles, Jpad / 16);
      k_lstm_gemm<<<g, 64, 0, stream>>>(Dbuf, Wlstm, lb, c,
                                        out + h_off[i], out + c_off[i],
                                        S, lS, CpadL, CH, Jpad, M);
    }
  }
}

// Round 3
// 1627.792 us; speedup vs baseline: 1.6946x; 1.4456x over previous
//
#include <hip/hip_runtime.h>
#include <math.h>

typedef _Float16 f16;
typedef _Float16 f16x8 __attribute__((ext_vector_type(8)));
typedef float f32x4 __attribute__((ext_vector_type(4)));

__device__ __forceinline__ float sigmoidf_(float x) { return 1.0f / (1.0f + expf(-x)); }

#define NB 8  // batch

// ---------------- staging: NCHW f32 -> NHWC f16 (parametric pad, padded channels) ----
__global__ void k_nchw2nhwc(const float* __restrict__ in, f16* __restrict__ out,
                            int C, int S, int Cpad, int coff, int Wp, int pad) {
  __shared__ float tile[16][17];
  int xt = blockIdx.x;          // x tile
  int ct = blockIdx.y;          // c tile
  int by = blockIdx.z;          // b*S + y
  int b = by / S, y = by % S;
  int x0 = xt * 16, c0 = ct * 16;
  int tx = threadIdx.x & 15, tc = threadIdx.x >> 4;
  float v = 0.f;
  if (c0 + tc < C && x0 + tx < S)
    v = in[(((size_t)b * C + c0 + tc) * S + y) * S + x0 + tx];
  tile[tc][tx] = v;
  __syncthreads();
  int tcc = threadIdx.x & 15;   // channel within tile (fastest -> coalesced writes)
  int txx = threadIdx.x >> 4;   // x within tile
  if (c0 + tcc < C && x0 + txx < S)
    out[(((size_t)b * Wp + y + pad) * Wp + (x0 + txx + pad)) * Cpad + coff + c0 + tcc]
        = (f16)tile[tcc][txx];
}

// ---------------- weight re-layouts (pads written as zero) ---------------------------
__global__ void k_wlstm(const float* __restrict__ w, f16* __restrict__ wt,
                        int CH, int CH2, int Jpad, int Cpad) {
  int idx = blockIdx.x * blockDim.x + threadIdx.x;
  int total = 9 * 4 * Jpad * Cpad;
  if (idx >= total) return;
  int ci = idx % Cpad; int t = idx / Cpad;
  int j = t % Jpad; t /= Jpad;
  int g = t % 4; int kk = t / 4;
  float v = 0.f;
  if (j < CH && ci < CH2)
    v = w[((size_t)(g * CH + j) * CH2 + ci) * 9 + kk];
  wt[idx] = (f16)v;
}

__global__ void k_wsum(const float* __restrict__ w, f16* __restrict__ wt,
                       int C8, int C, int Npad, int Cpad) {
  int idx = blockIdx.x * blockDim.x + threadIdx.x;
  int total = 9 * Npad * Cpad;
  if (idx >= total) return;
  int ci = idx % Cpad; int t = idx / Cpad;
  int co = t % Npad; int kk = t / Npad;
  float v = 0.f;
  if (co < C8 && ci < C)
    v = w[((size_t)co * C + ci) * 9 + kk];
  wt[idx] = (f16)v;
}

// ---------------- summary conv GEMM: 4-wave block, in-block K-split, LDS reduce ------
// block = 256 thr (4 waves). All waves share the 64m x 64n tile; wave w accumulates
// K-iters [w*T4, (w+1)*T4) of the flattened (kk, cb) space, then 2-phase LDS reduce;
// wave w finalizes rows s=w.
__global__ void __launch_bounds__(256)
k_conv_gemm(const f16* __restrict__ A,     // (B,Sp,Sp,CpadX) pad1
            const f16* __restrict__ Wt,    // [kk][Npad][CpadX]
            const float* __restrict__ bias,
            f16* __restrict__ D,           // (B,Sp,Sp,CpadL) pad1, channels [0,C8)
            int S, int lS, int CpadX, int CpadL, int C8, int Npad, int M) {
  int w = threadIdx.x >> 6;
  int lane = threadIdx.x & 63;
  int quad = lane >> 4, r = lane & 15;
  int mtile = blockIdx.x, ntile = blockIdx.y;
  int Sp = S + 2;
  size_t abase[4];
#pragma unroll
  for (int s = 0; s < 4; s++) {
    int m = mtile * 64 + s * 16 + r;
    if (m >= M) m = M - 1;
    int b = m >> (2 * lS);
    int rem = m & ((1 << (2 * lS)) - 1);
    int y = rem >> lS, x = rem & ((1 << lS) - 1);
    abase[s] = (((size_t)b * Sp + y) * Sp + x) * CpadX + quad * 8;
  }
  f32x4 acc[4][4] = {};
  int n0 = ntile * 64;
  int KB = CpadX >> 5;
  int T = 9 * KB;
  int T4 = (T + 3) >> 2;
  int it = w * T4;
  int itEnd = (T < it + T4) ? T : it + T4;
  int nIt = itEnd - it;
  int kk = it / KB;
  int cb = it - kk * KB;

#define CG_LOAD(AF, BF) do { \
    int ky_ = kk / 3, kx_ = kk - 3 * ky_; \
    size_t aoff_ = ((size_t)(ky_ * Sp + kx_)) * CpadX + (size_t)cb * 32; \
    const f16* wp_ = Wt + ((size_t)kk * Npad + n0 + r) * CpadX + quad * 8 + (size_t)cb * 32; \
    _Pragma("unroll") for (int s_ = 0; s_ < 4; s_++) \
      AF[s_] = *(const f16x8*)(A + abase[s_] + aoff_); \
    _Pragma("unroll") for (int t_ = 0; t_ < 4; t_++) \
      BF[t_] = *(const f16x8*)(wp_ + (size_t)t_ * 16 * CpadX); \
  } while (0)
#define CG_ADV() do { cb++; if (cb == KB) { cb = 0; kk++; } } while (0)
#define CG_MF(AF, BF) do { \
    _Pragma("unroll") for (int s_ = 0; s_ < 4; s_++) \
    _Pragma("unroll") for (int t_ = 0; t_ < 4; t_++) \
      acc[s_][t_] = __builtin_amdgcn_mfma_f32_16x16x32_f16(AF[s_], BF[t_], acc[s_][t_], 0, 0, 0); \
  } while (0)

  {
    f16x8 a0[4], b0[4], a1[4], b1[4];
    if (nIt > 0) {
      CG_LOAD(a0, b0); CG_ADV();
      int rem = nIt - 1;
      while (rem >= 2) {
        CG_LOAD(a1, b1); CG_ADV();
        CG_MF(a0, b0);
        CG_LOAD(a0, b0); CG_ADV();
        CG_MF(a1, b1);
        rem -= 2;
      }
      if (rem == 1) { CG_LOAD(a1, b1); CG_MF(a0, b0); CG_MF(a1, b1); }
      else { CG_MF(a0, b0); }
    }
  }
#undef CG_LOAD
#undef CG_ADV
#undef CG_MF

  // 2-phase LDS reduce: phase A handles s=0,1; phase B s=2,3. Wave w owns s=w.
  __shared__ f32x4 red[4][2][4][64];  // [wave][s-half][t][lane] = 32 KB
#pragma unroll
  for (int sh = 0; sh < 2; sh++)
#pragma unroll
    for (int t = 0; t < 4; t++)
      red[w][sh][t][lane] = acc[sh][t];
  __syncthreads();
  f32x4 accR[4];
  if (w < 2) {
#pragma unroll
    for (int t = 0; t < 4; t++)
      accR[t] = red[0][w][t][lane] + red[1][w][t][lane] + red[2][w][t][lane] + red[3][w][t][lane];
  }
  __syncthreads();
#pragma unroll
  for (int sh = 0; sh < 2; sh++)
#pragma unroll
    for (int t = 0; t < 4; t++)
      red[w][sh][t][lane] = acc[2 + sh][t];
  __syncthreads();
  if (w >= 2) {
#pragma unroll
    for (int t = 0; t < 4; t++)
      accR[t] = red[0][w - 2][t][lane] + red[1][w - 2][t][lane] + red[2][w - 2][t][lane] + red[3][w - 2][t][lane];
  }

  // epilogue: wave w writes rows s=w
#pragma unroll
  for (int i = 0; i < 4; i++) {
    int m = mtile * 64 + w * 16 + quad * 4 + i;
    if (m >= M) continue;
    int b = m >> (2 * lS);
    int rem = m & ((1 << (2 * lS)) - 1);
    int y = rem >> lS, x = rem & ((1 << lS) - 1);
    size_t dbase = (((size_t)b * Sp + y + 1) * Sp + (x + 1)) * CpadL;
#pragma unroll
    for (int t = 0; t < 4; t++) {
      int co = n0 + t * 16 + r;
      if (co < C8) {
        float v = accR[t][i] + bias[co];
        D[dbase + co] = (f16)fmaxf(v, 0.f);
      }
    }
  }
}

// ---------------- LSTM conv GEMM: 4-wave block, in-block K-split, fused gates --------
__global__ void __launch_bounds__(256)
k_lstm_gemm(const f16* __restrict__ A,     // (B,Sp,Sp,CpadL) staged lstm_in
            const f16* __restrict__ Wt,    // [kk][4][Jpad][CpadL]
            const float* __restrict__ lb,  // (4CH)
            const float* __restrict__ cprev,  // (B,CH,S,S) f32
            float* __restrict__ hout, float* __restrict__ cout,
            int S, int lS, int CpadL, int CH, int Jpad, int M) {
  int w = threadIdx.x >> 6;
  int lane = threadIdx.x & 63;
  int quad = lane >> 4, r = lane & 15;
  int mtile = blockIdx.x, jt = blockIdx.y;
  int j0 = jt * 16;
  int Sp = S + 2;
  size_t abase[4];
#pragma unroll
  for (int s = 0; s < 4; s++) {
    int m = mtile * 64 + s * 16 + r;
    if (m >= M) m = M - 1;
    int b = m >> (2 * lS);
    int rem = m & ((1 << (2 * lS)) - 1);
    int y = rem >> lS, x = rem & ((1 << lS) - 1);
    abase[s] = (((size_t)b * Sp + y) * Sp + x) * CpadL + quad * 8;
  }
  f32x4 acc[4][4] = {};  // [msub][gate]
  int KB = CpadL >> 5;
  int T = 9 * KB;
  int T4 = (T + 3) >> 2;
  int it = w * T4;
  int itEnd = (T < it + T4) ? T : it + T4;
  int nIt = itEnd - it;
  int kk = it / KB;
  int cb = it - kk * KB;

#define LG_LOAD(AF, BF) do { \
    int ky_ = kk / 3, kx_ = kk - 3 * ky_; \
    size_t aoff_ = ((size_t)(ky_ * Sp + kx_)) * CpadL + (size_t)cb * 32; \
    const f16* wp_ = Wt + (((size_t)kk * 4) * Jpad + j0 + r) * CpadL + quad * 8 + (size_t)cb * 32; \
    _Pragma("unroll") for (int s_ = 0; s_ < 4; s_++) \
      AF[s_] = *(const f16x8*)(A + abase[s_] + aoff_); \
    _Pragma("unroll") for (int g_ = 0; g_ < 4; g_++) \
      BF[g_] = *(const f16x8*)(wp_ + (size_t)g_ * Jpad * CpadL); \
  } while (0)
#define LG_ADV() do { cb++; if (cb == KB) { cb = 0; kk++; } } while (0)
#define LG_MF(AF, BF) do { \
    _Pragma("unroll") for (int s_ = 0; s_ < 4; s_++) \
    _Pragma("unroll") for (int g_ = 0; g_ < 4; g_++) \
      acc[s_][g_] = __builtin_amdgcn_mfma_f32_16x16x32_f16(AF[s_], BF[g_], acc[s_][g_], 0, 0, 0); \
  } while (0)

  {
    f16x8 a0[4], b0[4], a1[4], b1[4];
    if (nIt > 0) {
      LG_LOAD(a0, b0); LG_ADV();
      int rem = nIt - 1;
      while (rem >= 2) {
        LG_LOAD(a1, b1); LG_ADV();
        LG_MF(a0, b0);
        LG_LOAD(a0, b0); LG_ADV();
        LG_MF(a1, b1);
        rem -= 2;
      }
      if (rem == 1) { LG_LOAD(a1, b1); LG_MF(a0, b0); LG_MF(a1, b1); }
      else { LG_MF(a0, b0); }
    }
  }
#undef LG_LOAD
#undef LG_ADV
#undef LG_MF

  __shared__ f32x4 red[4][2][4][64];  // 32 KB
#pragma unroll
  for (int sh = 0; sh < 2; sh++)
#pragma unroll
    for (int g = 0; g < 4; g++)
      red[w][sh][g][lane] = acc[sh][g];
  __syncthreads();
  f32x4 accR[4];
  if (w < 2) {
#pragma unroll
    for (int g = 0; g < 4; g++)
      accR[g] = red[0][w][g][lane] + red[1][w][g][lane] + red[2][w][g][lane] + red[3][w][g][lane];
  }
  __syncthreads();
#pragma unroll
  for (int sh = 0; sh < 2; sh++)
#pragma unroll
    for (int g = 0; g < 4; g++)
      red[w][sh][g][lane] = acc[2 + sh][g];
  __syncthreads();
  if (w >= 2) {
#pragma unroll
    for (int g = 0; g < 4; g++)
      accR[g] = red[0][w - 2][g][lane] + red[1][w - 2][g][lane] + red[2][w - 2][g][lane] + red[3][w - 2][g][lane];
  }

  int j = j0 + r;
  if (j >= CH) return;
  float bi = lb[j];
  float bf_ = lb[CH + j];
  float bo = lb[2 * CH + j];
  float bg = lb[3 * CH + j];
#pragma unroll
  for (int i = 0; i < 4; i++) {
    int m = mtile * 64 + w * 16 + quad * 4 + i;
    if (m >= M) continue;
    int b = m >> (2 * lS);
    int rem = m & ((1 << (2 * lS)) - 1);
    int y = rem >> lS, x = rem & ((1 << lS) - 1);
    size_t o = (((size_t)b * CH + j) * S + y) * S + x;
    float ig = sigmoidf_(accR[0][i] + bi);
    float fg = sigmoidf_(accR[1][i] + bf_);
    float og = sigmoidf_(accR[2][i] + bo);
    float gg = tanhf(accR[3][i] + bg);
    float cn = fg * cprev[o] + ig * gg;
    hout[o] = og * tanhf(cn);
    cout[o] = cn;
  }
}

// ---------------- correlation (small levels 3-5): f32 exact, f16 copy into staged D --
__global__ void k_corr(const float* __restrict__ f1, const float* __restrict__ f2,
                       float* __restrict__ corr_out, f16* __restrict__ D,
                       int C, int S, int CpadL, int C8) {
  int idx = blockIdx.x * blockDim.x + threadIdx.x;
  int total = NB * 49 * S * S;
  if (idx >= total) return;
  int px = idx % S; int t = idx / S;
  int py = t % S; t /= S;
  int d = t % 49; int b = t / 49;
  int qy = py + d / 7 - 3;
  int qx = px + d % 7 - 3;

  float acc = 0.f;
  if (qy >= 0 && qy < S && qx >= 0 && qx < S) {
    const float* p1 = f1 + ((size_t)b * C * S + py) * S + px;
    const float* p2 = f2 + ((size_t)b * C * S + qy) * S + qx;
    size_t cs = (size_t)S * S;
    for (int ci = 0; ci < C; ci++) {
      acc += p1[(size_t)ci * cs] * p2[(size_t)ci * cs];
    }
  }
  float lr = (acc > 0.f) ? acc : 0.01f * acc;
  corr_out[idx] = lr;
  int Sp = S + 2;
  D[(((size_t)b * Sp + py + 1) * Sp + (px + 1)) * CpadL + C8 + d] = (f16)lr;
}

// ---------------- correlation (big levels 0-2): banded MFMA Gram tiles ---------------
template<int S>
__global__ void __launch_bounds__(256)
k_corr_mfma(const f16* __restrict__ A,     // (B,S+2,S+2,C)
            const f16* __restrict__ A2,    // (B,S+6,S+6,C)
            float* __restrict__ corr_out,  // (B,49,S,S)
            f16* __restrict__ D,           // (B,S+2,S+2,CpadL), channels [C8,C8+49)
            int C, int CpadL, int C8) {
  constexpr int XT = S / 16;
  constexpr int Sp = S + 2, Sq = S + 6;
  int nb = gridDim.x;
  int eb = (blockIdx.x % 8) * (nb / 8) + blockIdx.x / 8;
  int wid = eb * 4 + (threadIdx.x >> 6);
  int lane = threadIdx.x & 63;
  int quad = lane >> 4, r = lane & 15;
  int xt = wid % XT; int t1 = wid / XT;
  int y = t1 % S; int b = t1 / S;
  int x0 = xt * 16;

  const f16* pa = A + (((size_t)b * Sp + (y + 1)) * Sp + (x0 + r + 1)) * C + quad * 8;
  int xs1 = x0 + 16 + r; if (xs1 > S + 5) xs1 = S + 5;
  size_t off0 = (size_t)(x0 + r) * C + (size_t)quad * 8;
  size_t off1 = (size_t)xs1 * C + (size_t)quad * 8;
  const f16* pb = A2 + ((size_t)b * Sq + y) * Sq * C;

  f32x4 acc[7][2] = {};
  for (int cb = 0; cb < C; cb += 32) {
    f16x8 af = *(const f16x8*)(pa + cb);
#pragma unroll
    for (int dyo = 0; dyo < 7; dyo++) {
      const f16* pr = pb + (size_t)dyo * Sq * C + cb;
      f16x8 b0 = *(const f16x8*)(pr + off0);
      f16x8 b1 = *(const f16x8*)(pr + off1);
      acc[dyo][0] = __builtin_amdgcn_mfma_f32_16x16x32_f16(af, b0, acc[dyo][0], 0, 0, 0);
      acc[dyo][1] = __builtin_amdgcn_mfma_f32_16x16x32_f16(af, b1, acc[dyo][1], 0, 0, 0);
    }
  }
#pragma unroll
  for (int dyo = 0; dyo < 7; dyo++) {
#pragma unroll
    for (int t = 0; t < 2; t++) {
#pragma unroll
      for (int i = 0; i < 4; i++) {
        int ml = quad * 4 + i;
        int dxo = r - ml + t * 16;
        if (dxo < 0 || dxo > 6) continue;
        float v = acc[dyo][t][i];
        float lr = (v > 0.f) ? v : 0.01f * v;
        int d = dyo * 7 + dxo;
        int x = x0 + ml;
        corr_out[(((size_t)b * 49 + d) * S + y) * S + x] = lr;
        D[(((size_t)b * Sp + y + 1) * Sp + (x + 1)) * CpadL + C8 + d] = (f16)lr;
      }
    }
  }
}

extern "C" void kernel_launch(void* const* d_in, const int* in_sizes, int n_in,
                              void* d_out, int out_size, void* d_ws, size_t ws_size,
                              hipStream_t stream) {
  (void)in_sizes; (void)n_in; (void)out_size; (void)ws_size;
  static const int CINa[6] = {512, 1024, 512, 256, 256, 256};
  static const int Sa[6]   = {64, 32, 16, 8, 4, 2};
  static const int lSa[6]  = {6, 5, 4, 3, 2, 1};
  static const int CHa[6]  = {113, 177, 113, 81, 81, 81};
  static const int CpadLa[6] = {256, 384, 256, 192, 192, 192};  // 2*CH -> mult of 32
  static const int Jpada[6]  = {128, 192, 128, 96, 96, 96};     // CH -> mult of 16
  const int B = 8;

  size_t h_off[6], c_off[6], corr_off[6];
  size_t off = 0;
  for (int i = 0; i < 6; i++) { h_off[i] = off;    off += (size_t)B * CHa[i] * Sa[i] * Sa[i]; }
  for (int i = 0; i < 6; i++) { c_off[i] = off;    off += (size_t)B * CHa[i] * Sa[i] * Sa[i]; }
  for (int i = 0; i < 6; i++) { corr_off[i] = off; off += (size_t)B * 49 * Sa[i] * Sa[i]; }

  float* out = (float*)d_out;
  char* ws = (char*)d_ws;
  // arena: A (x NHWC pad1) 36MB | D (lstm_in NHWC pad1) 18MB | Wsum 3MB | Wlstm 6MB |
  //        A2 (xp NHWC pad3, levels 0-2) max 40.2MB  -> total ~103.3MB
  const size_t offA = 0;
  const size_t offD = 37748736;
  const size_t offWs = offD + 18874368;
  const size_t offWl = offWs + 3145728;
  const size_t offA2 = offWl + 6291456;

  for (int i = 0; i < 6; i++) {
    const float* x  = (const float*)d_in[8 * i + 0];
    const float* xp = (const float*)d_in[8 * i + 1];
    const float* h  = (const float*)d_in[8 * i + 2];
    const float* c  = (const float*)d_in[8 * i + 3];
    const float* sw = (const float*)d_in[8 * i + 4];
    const float* sb = (const float*)d_in[8 * i + 5];
    const float* lw = (const float*)d_in[8 * i + 6];
    const float* lb = (const float*)d_in[8 * i + 7];
    int C = CINa[i], S = Sa[i], lS = lSa[i], CH = CHa[i], C8 = C / 8;
    int CH2 = 2 * CH, CpadL = CpadLa[i], Jpad = Jpada[i];
    int Sp = S + 2;
    int Npad = (C8 + 63) / 64 * 64;
    int M = B * S * S;
    int Mtiles = (M + 63) / 64;

    f16* Abuf = (f16*)(ws + offA);
    f16* Dbuf = (f16*)(ws + offD);
    f16* Wsum = (f16*)(ws + offWs);
    f16* Wlstm = (f16*)(ws + offWl);
    f16* A2buf = (f16*)(ws + offA2);

    size_t sizeA = (size_t)B * Sp * Sp * C * 2;
    size_t sizeD = (size_t)B * Sp * Sp * CpadL * 2;
    hipMemsetAsync(Abuf, 0, sizeA, stream);
    hipMemsetAsync(Dbuf, 0, sizeD, stream);

    // x -> A (NHWC f16, pad1); CpadX == C (all multiples of 32)
    {
      dim3 g((S + 15) / 16, (C + 15) / 16, B * S);
      k_nchw2nhwc<<<g, 256, 0, stream>>>(x, Abuf, C, S, C, 0, Sp, 1);
    }
    // summary weights
    {
      int tot = 9 * Npad * C;
      k_wsum<<<(tot + 255) / 256, 256, 0, stream>>>(sw, Wsum, C8, C, Npad, C);
    }
    // summary GEMM -> D channels [0, C8)
    {
      dim3 g(Mtiles, Npad / 64);
      k_conv_gemm<<<g, 256, 0, stream>>>(Abuf, Wsum, sb, Dbuf, S, lS, C, CpadL, C8, Npad, M);
    }
    // correlation -> d_out (f32) + D channels [C8, C8+49)
    if (i < 3) {
      int Sq = S + 6;
      size_t sizeA2 = (size_t)B * Sq * Sq * C * 2;
      hipMemsetAsync(A2buf, 0, sizeA2, stream);
      {
        dim3 g((S + 15) / 16, (C + 15) / 16, B * S);
        k_nchw2nhwc<<<g, 256, 0, stream>>>(xp, A2buf, C, S, C, 0, Sq, 3);
      }
      int blocks = B * S * (S / 16) / 4;   // one wave per 16-pixel A-tile
      if (i == 0)
        k_corr_mfma<64><<<blocks, 256, 0, stream>>>(Abuf, A2buf, out + corr_off[i], Dbuf,
                                                    C, CpadL, C8);
      else if (i == 1)
        k_corr_mfma<32><<<blocks, 256, 0, stream>>>(Abuf, A2buf, out + corr_off[i], Dbuf,
                                                    C, CpadL, C8);
      else
        k_corr_mfma<16><<<blocks, 256, 0, stream>>>(Abuf, A2buf, out + corr_off[i], Dbuf,
                                                    C, CpadL, C8);
    } else {
      int tot = B * 49 * S * S;
      k_corr<<<(tot + 255) / 256, 256, 0, stream>>>(x, xp, out + corr_off[i], Dbuf,
                                                    C, S, CpadL, C8);
    }
    // h -> D channels [C8+49, 2CH)
    {
      dim3 g((S + 15) / 16, (CH + 15) / 16, B * S);
      k_nchw2nhwc<<<g, 256, 0, stream>>>(h, Dbuf, CH, S, CpadL, C8 + 49, Sp, 1);
    }
    // lstm weights
    {
      int tot = 9 * 4 * Jpad * CpadL;
      k_wlstm<<<(tot + 255) / 256, 256, 0, stream>>>(lw, Wlstm, CH, CH2, Jpad, CpadL);
    }
    // LSTM GEMM + fused gates
    {
      dim3 g(Mtiles, Jpad / 16);
      k_lstm_gemm<<<g, 256, 0, stream>>>(Dbuf, Wlstm, lb, c,
                                         out + h_off[i], out + c_off[i],
                                         S, lS, CpadL, CH, Jpad, M);
    }
  }
}